// Round 7
// baseline (1550.000 us; speedup 1.0000x reference)
//
#include <hip/hip_runtime.h>
#include <math.h>

// Problem dims: B=16, C=256, H=W=128
#define BATCHES      16
#define CHANNELS     256
#define HW           (128 * 128)                 // 16384 floats per channel
#define VEC_PER_BATCH (1 << 20)                  // float4 per (input,batch) = 2^20
#define T             256                        // threads per block
#define NB            512                        // persistent blocks (2/CU, co-resident
                                                 // even at 256 VGPR: 512 regs/SIMD / 256
                                                 // = 2 waves/SIMD = 8 waves/CU = 2 blocks)
#define VEC_PER_BLK   (VEC_PER_BATCH / NB)       // 2048 float4 per input per block
#define K4            (VEC_PER_BLK / T)          // 8 float4 per thread per input

// ws layout:
//   floats [0 .. 16*3*512)   : per-phase block partials  (98304 B)
//   uint   at byte 98304     : 16 phase counters (64 B, memset to 0 each call)
#define PARTIALS_FLOATS (BATCHES * 3 * NB)
#define CNT_BYTE_OFF    (PARTIALS_FLOATS * 4)

typedef float f32x4 __attribute__((ext_vector_type(4)));

// ---------------------------------------------------------------------------
// Fused persistent kernel: per batch-phase, each block loads its chunk of all
// 3 inputs into registers ONCE, computes weighted partials, group-barriers on
// an agent-scope counter, folds partials deterministically -> sigmoid
// attention, then applies + writes output straight from registers.
// Inputs are read exactly once per call (768 MB instead of 1.54 GB).
// ---------------------------------------------------------------------------
__global__ __launch_bounds__(T, 2) void fusion_fused_kernel(
    const float4* __restrict__ gray,
    const float4* __restrict__ green,
    const float4* __restrict__ rgb,
    const float* __restrict__ conv_w,
    const float* __restrict__ conv_b,
    float* __restrict__ partials,     // [16][3][NB]
    unsigned int* __restrict__ cnt,   // [16], zeroed by memsetAsync each call
    float4* __restrict__ out)
{
    const int blk = blockIdx.x;
    const int t   = (int)threadIdx.x;
    const int wid = t >> 6;

    // Block covers 2048 float4 = 8192 floats = half a channel -> wave-uniform w.
    const float w    = conv_w[blk >> 1];
    const float bias = conv_b[0];

    __shared__ float red[3][T / 64];

    for (int p = 0; p < BATCHES; ++p) {
        const size_t base = (size_t)p * VEC_PER_BATCH + (size_t)blk * VEC_PER_BLK + t;

        // ---- load phase chunk into registers (96 floats payload) ----
        float4 dg[K4], dn[K4], dr[K4];
        #pragma unroll
        for (int k = 0; k < K4; ++k) dg[k] = gray [base + (size_t)k * T];
        #pragma unroll
        for (int k = 0; k < K4; ++k) dn[k] = green[base + (size_t)k * T];
        #pragma unroll
        for (int k = 0; k < K4; ++k) dr[k] = rgb  [base + (size_t)k * T];

        // ---- per-thread sums ----
        float sg = 0.f, sn = 0.f, sr = 0.f;
        #pragma unroll
        for (int k = 0; k < K4; ++k) {
            sg += (dg[k].x + dg[k].y) + (dg[k].z + dg[k].w);
            sn += (dn[k].x + dn[k].y) + (dn[k].z + dn[k].w);
            sr += (dr[k].x + dr[k].y) + (dr[k].z + dr[k].w);
        }

        // ---- wave64 reduce, 3 chains ----
        #pragma unroll
        for (int off = 32; off > 0; off >>= 1) {
            sg += __shfl_down(sg, off, 64);
            sn += __shfl_down(sn, off, 64);
            sr += __shfl_down(sr, off, 64);
        }
        if ((t & 63) == 0) { red[0][wid] = sg; red[1][wid] = sn; red[2][wid] = sr; }
        __syncthreads();

        // ---- thread 0: publish weighted block partials, arrive at barrier ----
        float* P = partials + (size_t)p * 3 * NB;
        if (t == 0) {
            float pg = ((red[0][0] + red[0][1]) + (red[0][2] + red[0][3])) * w;
            float pn = ((red[1][0] + red[1][1]) + (red[1][2] + red[1][3])) * w;
            float pr = ((red[2][0] + red[2][1]) + (red[2][2] + red[2][3])) * w;
            __hip_atomic_store(&P[0 * NB + blk], pg, __ATOMIC_RELAXED, __HIP_MEMORY_SCOPE_AGENT);
            __hip_atomic_store(&P[1 * NB + blk], pn, __ATOMIC_RELAXED, __HIP_MEMORY_SCOPE_AGENT);
            __hip_atomic_store(&P[2 * NB + blk], pr, __ATOMIC_RELAXED, __HIP_MEMORY_SCOPE_AGENT);
            __threadfence();
            atomicAdd(&cnt[p], 1u);
            // spin until all NB blocks published this phase
            while (__hip_atomic_load(&cnt[p], __ATOMIC_RELAXED, __HIP_MEMORY_SCOPE_AGENT) < NB)
                __builtin_amdgcn_s_sleep(2);
        }
        __syncthreads();
        __threadfence();

        // ---- fold partials (deterministic fixed order), all blocks identical ----
        float a[3];
        #pragma unroll
        for (int i = 0; i < 3; ++i) {
            const float* Pi = P + (size_t)i * NB;
            float v = __hip_atomic_load(&Pi[t],       __ATOMIC_RELAXED, __HIP_MEMORY_SCOPE_AGENT)
                    + __hip_atomic_load(&Pi[t + 256], __ATOMIC_RELAXED, __HIP_MEMORY_SCOPE_AGENT);
            #pragma unroll
            for (int off = 32; off > 0; off >>= 1) v += __shfl_down(v, off, 64);
            if ((t & 63) == 0) red[i][wid] = v;
        }
        __syncthreads();
        #pragma unroll
        for (int i = 0; i < 3; ++i) {
            float tot = ((red[i][0] + red[i][1]) + (red[i][2] + red[i][3]));
            float logit = tot * (1.0f / (float)HW) + bias;
            a[i] = 1.0f / (1.0f + expf(-logit));
        }

        // ---- apply + store from registers (no second read) ----
        #pragma unroll
        for (int k = 0; k < K4; ++k) {
            f32x4 o;
            o.x = dg[k].x * a[0] + 10.0f * (dn[k].x * a[1] + dr[k].x * a[2]);
            o.y = dg[k].y * a[0] + 10.0f * (dn[k].y * a[1] + dr[k].y * a[2]);
            o.z = dg[k].z * a[0] + 10.0f * (dn[k].z * a[1] + dr[k].z * a[2]);
            o.w = dg[k].w * a[0] + 10.0f * (dn[k].w * a[1] + dr[k].w * a[2]);
            __builtin_nontemporal_store(o, reinterpret_cast<f32x4*>(&out[base + (size_t)k * T]));
        }

        // protect red[] (re-written next phase) against stragglers of this phase
        __syncthreads();
    }
}

extern "C" void kernel_launch(void* const* d_in, const int* in_sizes, int n_in,
                              void* d_out, int out_size, void* d_ws, size_t ws_size,
                              hipStream_t stream) {
    const float4* gray   = (const float4*)d_in[0];
    const float4* green  = (const float4*)d_in[1];
    const float4* rgb    = (const float4*)d_in[2];
    const float*  conv_w = (const float*)d_in[3];
    const float*  conv_b = (const float*)d_in[4];
    float4* out = (float4*)d_out;

    float*        partials = (float*)d_ws;
    unsigned int* cnt      = (unsigned int*)((char*)d_ws + CNT_BYTE_OFF);

    // Zero the 16 phase counters (graph-capture-legal async memset).
    hipMemsetAsync(cnt, 0, BATCHES * sizeof(unsigned int), stream);

    fusion_fused_kernel<<<NB, T, 0, stream>>>(
        gray, green, rgb, conv_w, conv_b, partials, cnt, out);
}